// Round 1
// baseline (1493.633 us; speedup 1.0000x reference)
//
#include <hip/hip_runtime.h>

// ---------------------------------------------------------------------------
// GFGCN (3-layer graph filter GCN), N=8192, dims 512->128->128->64, K=3.
// All heavy GEMMs in bf16 MFMA (16x16x32), fp32 accumulate.
// Verified MFMA layouts (learn_hip m89/m91/m120):
//   A-frag : lane holds A[m = lane&15][k = (lane>>4)*8 + j], j=0..7
//   B-frag : lane holds B[k = (lane>>4)*8 + j][n = lane&15]
//   C/D    : lane,reg r -> row = (lane>>4)*4 + r, col = lane&15
// ---------------------------------------------------------------------------

typedef __attribute__((ext_vector_type(4))) float  f32x4;
typedef __attribute__((ext_vector_type(8))) __bf16 bf16x8;
typedef __attribute__((ext_vector_type(4))) __bf16 bf16x4;

// fp32 -> bf16 converter, float4 in / bf16x4 out, grid-stride
__global__ void cvt_f32_bf16(const float4* __restrict__ in,
                             bf16x4* __restrict__ out, int n4) {
    int i  = blockIdx.x * blockDim.x + threadIdx.x;
    int st = gridDim.x * blockDim.x;
    for (; i < n4; i += st) {
        float4 v = in[i];
        bf16x4 o;
        o[0] = (__bf16)v.x; o[1] = (__bf16)v.y;
        o[2] = (__bf16)v.z; o[3] = (__bf16)v.w;
        out[i] = o;
    }
}

// C[M,N] = A[M,K] @ B[K,N]  (row-major bf16 in, fp32 accum)
// COMBINE: out = h0*Y0 + h1*Y1 + h2*acc + bias  (+ReLU), else out = acc.
// Tile: 64x64, BK=64, 256 threads (4 waves, each wave a 32x32 subtile).
// All problem dims here are multiples of 64 -> no bounds checks.
template<int COMBINE, int RELU, int OUTF32>
__global__ __launch_bounds__(256)
void gemm_bf16(const __bf16* __restrict__ A, const __bf16* __restrict__ B,
               __bf16* __restrict__ Cb, float* __restrict__ Cf,
               const __bf16* __restrict__ Y0, const __bf16* __restrict__ Y1,
               const float* __restrict__ h, const float* __restrict__ bias,
               int M, int N, int Kd)
{
    // +8 bf16 pad (16 B) keeps 16B alignment for b128 reads and breaks the
    // 128B-row-stride bank pathology (stride 144 B -> 4-bank rotation/row).
    __shared__ alignas(16) __bf16 As[64][72];   // As[m][k]
    __shared__ alignas(16) __bf16 Bs[64][72];   // Bs[n][k]  (transposed)

    const int tid  = threadIdx.x;
    const int m0   = blockIdx.x * 64;
    const int n0   = blockIdx.y * 64;

    const int w    = tid >> 6;          // wave 0..3
    const int lane = tid & 63;
    const int l15  = lane & 15;
    const int quad = lane >> 4;         // 0..3
    const int wr   = (w >> 1) * 32;     // wave row offset in tile
    const int wc   = (w & 1)  * 32;     // wave col offset in tile

    // A staging: thread -> rows (tid>>3) and (tid>>3)+32, 8 bf16 (16 B) each
    const int arow = tid >> 3;          // 0..31
    const int acol = (tid & 7) * 8;     // 0..56
    // B staging (with transpose): thread -> 4 k-rows x 4 n-cols
    const int brow = tid >> 4;          // 0..15
    const int bcol = (tid & 15) * 4;    // 0..60

    f32x4 acc00 = {0.f, 0.f, 0.f, 0.f};
    f32x4 acc01 = acc00, acc10 = acc00, acc11 = acc00;

    for (int k0 = 0; k0 < Kd; k0 += 64) {
        // ---- stage A tile (64x64) ----
        {
            const uint4* g0 = (const uint4*)(A + (size_t)(m0 + arow)      * Kd + k0 + acol);
            const uint4* g1 = (const uint4*)(A + (size_t)(m0 + arow + 32) * Kd + k0 + acol);
            *(uint4*)(&As[arow][acol])      = *g0;
            *(uint4*)(&As[arow + 32][acol]) = *g1;
        }
        // ---- stage B tile (64 k-rows x 64 n-cols), transposed into Bs[n][k] ----
        #pragma unroll
        for (int kk = 0; kk < 64; kk += 16) {
            const int kr = brow + kk;
            bf16x4 v = *(const bf16x4*)(B + (size_t)(k0 + kr) * N + n0 + bcol);
            Bs[bcol + 0][kr] = v[0];
            Bs[bcol + 1][kr] = v[1];
            Bs[bcol + 2][kr] = v[2];
            Bs[bcol + 3][kr] = v[3];
        }
        __syncthreads();

        // ---- MFMA over the 64-deep K chunk (2 k-steps of 32) ----
        #pragma unroll
        for (int ks = 0; ks < 64; ks += 32) {
            bf16x8 a0 = *(const bf16x8*)(&As[wr +      l15][ks + quad * 8]);
            bf16x8 a1 = *(const bf16x8*)(&As[wr + 16 + l15][ks + quad * 8]);
            bf16x8 b0 = *(const bf16x8*)(&Bs[wc +      l15][ks + quad * 8]);
            bf16x8 b1 = *(const bf16x8*)(&Bs[wc + 16 + l15][ks + quad * 8]);
            acc00 = __builtin_amdgcn_mfma_f32_16x16x32_bf16(a0, b0, acc00, 0, 0, 0);
            acc01 = __builtin_amdgcn_mfma_f32_16x16x32_bf16(a0, b1, acc01, 0, 0, 0);
            acc10 = __builtin_amdgcn_mfma_f32_16x16x32_bf16(a1, b0, acc10, 0, 0, 0);
            acc11 = __builtin_amdgcn_mfma_f32_16x16x32_bf16(a1, b1, acc11, 0, 0, 0);
        }
        __syncthreads();
    }

    // ---- epilogue ----
    float h0 = 0.f, h1v = 0.f, h2v = 0.f;
    if (COMBINE) { h0 = h[0]; h1v = h[1]; h2v = h[2]; }

    f32x4 accs[2][2] = {{acc00, acc01}, {acc10, acc11}};
    #pragma unroll
    for (int ti = 0; ti < 2; ti++) {
        #pragma unroll
        for (int tj = 0; tj < 2; tj++) {
            const f32x4 a = accs[ti][tj];
            const int col = n0 + wc + tj * 16 + l15;
            const int rb  = m0 + wr + ti * 16 + quad * 4;
            #pragma unroll
            for (int r = 0; r < 4; r++) {
                const size_t idx = (size_t)(rb + r) * N + col;
                float v = a[r];
                if (COMBINE) {
                    v = h0 * (float)Y0[idx] + h1v * (float)Y1[idx] + h2v * v + bias[col];
                    if (RELU) v = fmaxf(v, 0.0f);
                }
                if (OUTF32) Cf[idx] = v;
                else        Cb[idx] = (__bf16)v;
            }
        }
    }
}

extern "C" void kernel_launch(void* const* d_in, const int* in_sizes, int n_in,
                              void* d_out, int out_size, void* d_ws, size_t ws_size,
                              hipStream_t stream) {
    const float* S  = (const float*)d_in[0];
    const float* X  = (const float*)d_in[1];
    const float* W1 = (const float*)d_in[2];
    const float* h1 = (const float*)d_in[3];
    const float* b1 = (const float*)d_in[4];
    const float* W2 = (const float*)d_in[5];
    const float* h2 = (const float*)d_in[6];
    const float* b2 = (const float*)d_in[7];
    const float* W3 = (const float*)d_in[8];
    const float* h3 = (const float*)d_in[9];
    const float* b3 = (const float*)d_in[10];
    float* out = (float*)d_out;

    const int Nn = 8192, IN = 512, HID = 128, OUT = 64;

    // workspace carve-up (256B aligned)
    char* ws = (char*)d_ws;
    size_t off = 0;
    auto carve = [&](size_t bytes) -> void* {
        void* p = ws + off;
        off += (bytes + 255) & ~(size_t)255;
        return p;
    };
    __bf16* Sb  = (__bf16*)carve((size_t)Nn * Nn  * 2);   // 134 MB
    __bf16* Xb  = (__bf16*)carve((size_t)Nn * IN  * 2);   // 8 MB
    __bf16* W1b = (__bf16*)carve((size_t)IN * HID * 2);
    __bf16* W2b = (__bf16*)carve((size_t)HID * HID * 2);
    __bf16* W3b = (__bf16*)carve((size_t)HID * OUT * 2);
    __bf16* Y0  = (__bf16*)carve((size_t)Nn * HID * 2);
    __bf16* Y1  = (__bf16*)carve((size_t)Nn * HID * 2);
    __bf16* Act = (__bf16*)carve((size_t)Nn * HID * 2);

    auto cvt = [&](const float* src, __bf16* dst, size_t n) {
        int n4 = (int)(n / 4);
        int blocks = (n4 + 255) / 256;
        cvt_f32_bf16<<<dim3(blocks), dim3(256), 0, stream>>>(
            (const float4*)src, (bf16x4*)dst, n4);
    };

    cvt(S,  Sb,  (size_t)Nn * Nn);
    cvt(X,  Xb,  (size_t)Nn * IN);
    cvt(W1, W1b, (size_t)IN * HID);
    cvt(W2, W2b, (size_t)HID * HID);
    cvt(W3, W3b, (size_t)HID * OUT);

    auto gemm = [&](const __bf16* A, const __bf16* B, __bf16* C,
                    int M, int N, int K) {
        gemm_bf16<0, 0, 0><<<dim3(M / 64, N / 64), dim3(256), 0, stream>>>(
            A, B, C, nullptr, nullptr, nullptr, nullptr, nullptr, M, N, K);
    };

    // ---- layer 1 ----
    gemm(Xb, W1b, Y0, Nn, HID, IN);         // Y0 = X @ W1
    gemm(Sb, Y0,  Y1, Nn, HID, Nn);         // Y1 = S @ Y0
    gemm_bf16<1, 1, 0><<<dim3(Nn / 64, HID / 64), dim3(256), 0, stream>>>(
        Sb, Y1, Act, nullptr, Y0, Y1, h1, b1, Nn, HID, Nn);  // Act = relu(h.Y + b1)

    // ---- layer 2 ----
    gemm(Act, W2b, Y0, Nn, HID, HID);
    gemm(Sb,  Y0,  Y1, Nn, HID, Nn);
    gemm_bf16<1, 1, 0><<<dim3(Nn / 64, HID / 64), dim3(256), 0, stream>>>(
        Sb, Y1, Act, nullptr, Y0, Y1, h2, b2, Nn, HID, Nn);

    // ---- layer 3 (no relu, fp32 out) ----
    gemm(Act, W3b, Y0, Nn, OUT, HID);
    gemm(Sb,  Y0,  Y1, Nn, OUT, Nn);
    gemm_bf16<1, 0, 1><<<dim3(Nn / 64, OUT / 64), dim3(256), 0, stream>>>(
        Sb, Y1, nullptr, out, Y0, Y1, h3, b3, Nn, OUT, Nn);

    (void)in_sizes; (void)n_in; (void)out_size; (void)ws_size;
}

// Round 2
// 892.385 us; speedup vs baseline: 1.6738x; 1.6738x over previous
//
#include <hip/hip_runtime.h>

// ---------------------------------------------------------------------------
// GFGCN round 2: barrier-free register-direct MFMA GEMMs + split-K.
//
// All GEMMs use 16x16x32 bf16 MFMA with frag layouts (m89/m91-verified):
//   A-frag : lane holds A[m = l15][k = quad*8 + j]   (16 B contiguous/lane)
//   B-frag : lane holds B[k = quad*8 + j][n = l15]   == Bt[n][k..k+7]
//   C/D    : reg r -> row = quad*4 + r, col = l15    (rows contiguous)
//
// Everything is kept "K-contiguous" (t-layout) so every frag load is one
// global_load_dwordx4 (64 B per quad, coalesced). No LDS, no barriers.
//   S-GEMM:  C[node][f] = S @ Yt;  A=S (row-major, ldA=8192), B=Yt[f][8192]
//            split-K -> fp32 partials P[s][f][node] (rows contiguous, x4)
//   W-GEMM:  Y0t[fo][node] = Wt @ U; A=Wt[fo][fi], B=U[node][fi] (normal!)
// ---------------------------------------------------------------------------

typedef __attribute__((ext_vector_type(4))) float  f32x4;
typedef __attribute__((ext_vector_type(8))) __bf16 bf16x8;
typedef __attribute__((ext_vector_type(4))) __bf16 bf16x4;

// ---- fp32 -> bf16, vectorized ----
__global__ void cvt_f32_bf16(const float4* __restrict__ in,
                             bf16x4* __restrict__ out, int n4) {
    int i  = blockIdx.x * blockDim.x + threadIdx.x;
    int st = gridDim.x * blockDim.x;
    for (; i < n4; i += st) {
        float4 v = in[i];
        bf16x4 o;
        o[0] = (__bf16)v.x; o[1] = (__bf16)v.y;
        o[2] = (__bf16)v.z; o[3] = (__bf16)v.w;
        out[i] = o;
    }
}

// ---- fp32 W[K][M] -> bf16 Wt[M][K] (tiny matrices) ----
__global__ void cvt_transpose(const float* __restrict__ W,
                              __bf16* __restrict__ Wt, int Kd, int Md) {
    int i = blockIdx.x * blockDim.x + threadIdx.x;
    if (i < Kd * Md) {
        int k = i / Md, m = i % Md;
        Wt[(size_t)m * Kd + k] = (__bf16)W[i];
    }
}

// ---------------------------------------------------------------------------
// Register-direct GEMM. Block = 4 waves stacked in M; wave covers
// (MF*16) rows x (NF*16) cols. BM = 64*MF, BN = 16*NF.
// grid: x = m-tile, y = n-tile, z = K-split.
// OUTMODE 0: fp32 partial, t-layout P[z][col][row] (row contiguous, f32x4)
// OUTMODE 1: bf16 row-major out[row][ldO + col] (scattered 2B, small data)
// ---------------------------------------------------------------------------
template<int MF, int NF, int OUTMODE>
__global__ __launch_bounds__(256)
void gemm_rd(const __bf16* __restrict__ A, const __bf16* __restrict__ Bt,
             void* __restrict__ out, int K, int Kchunk, int Mtot, int Ntot)
{
    const int lane = threadIdx.x & 63;
    const int w    = threadIdx.x >> 6;
    const int l15  = lane & 15;
    const int quad = lane >> 4;

    const int m_base = blockIdx.x * (64 * MF) + w * (16 * MF);
    const int n_base = blockIdx.y * (16 * NF);
    const int kstart = blockIdx.z * Kchunk;

    const __bf16* Ap[MF];
    #pragma unroll
    for (int mf = 0; mf < MF; mf++)
        Ap[mf] = A + (size_t)(m_base + mf * 16 + l15) * K + kstart + quad * 8;
    const __bf16* Bp[NF];
    #pragma unroll
    for (int nf = 0; nf < NF; nf++)
        Bp[nf] = Bt + (size_t)(n_base + nf * 16 + l15) * K + kstart + quad * 8;

    f32x4 acc[MF][NF];
    #pragma unroll
    for (int mf = 0; mf < MF; mf++)
        #pragma unroll
        for (int nf = 0; nf < NF; nf++)
            acc[mf][nf] = (f32x4){0.f, 0.f, 0.f, 0.f};

    #pragma unroll 2
    for (int ks = 0; ks < Kchunk; ks += 32) {
        bf16x8 a[MF], b[NF];
        #pragma unroll
        for (int mf = 0; mf < MF; mf++) a[mf] = *(const bf16x8*)(Ap[mf] + ks);
        #pragma unroll
        for (int nf = 0; nf < NF; nf++) b[nf] = *(const bf16x8*)(Bp[nf] + ks);
        #pragma unroll
        for (int mf = 0; mf < MF; mf++)
            #pragma unroll
            for (int nf = 0; nf < NF; nf++)
                acc[mf][nf] = __builtin_amdgcn_mfma_f32_16x16x32_bf16(
                    a[mf], b[nf], acc[mf][nf], 0, 0, 0);
    }

    if (OUTMODE == 0) {
        float* P = (float*)out + (size_t)blockIdx.z * Mtot * Ntot;
        #pragma unroll
        for (int mf = 0; mf < MF; mf++) {
            const int rowb = m_base + mf * 16 + quad * 4;
            #pragma unroll
            for (int nf = 0; nf < NF; nf++) {
                const int col = n_base + nf * 16 + l15;
                *(f32x4*)(P + (size_t)col * Mtot + rowb) = acc[mf][nf];
            }
        }
    } else {
        __bf16* O = (__bf16*)out;
        #pragma unroll
        for (int mf = 0; mf < MF; mf++) {
            const int rowb = m_base + mf * 16 + quad * 4;
            #pragma unroll
            for (int nf = 0; nf < NF; nf++) {
                const int col = n_base + nf * 16 + l15;
                #pragma unroll
                for (int r = 0; r < 4; r++)
                    O[(size_t)(rowb + r) * Ntot + col] = (__bf16)acc[mf][nf][r];
            }
        }
    }
}

// ---- sum SP split-partials -> bf16 t-layout Y[f][node] ----
__global__ void reduce_partials(const float* __restrict__ P,
                                __bf16* __restrict__ Y, int total4,
                                int SP, int MN) {
    int i = blockIdx.x * blockDim.x + threadIdx.x;
    if (i >= total4) return;
    size_t base = (size_t)i * 4;
    float4 s = *(const float4*)(P + base);
    for (int sp = 1; sp < SP; sp++) {
        float4 v = *(const float4*)(P + (size_t)sp * MN + base);
        s.x += v.x; s.y += v.y; s.z += v.z; s.w += v.w;
    }
    bf16x4 o; o[0] = (__bf16)s.x; o[1] = (__bf16)s.y;
    o[2] = (__bf16)s.z; o[3] = (__bf16)s.w;
    *(bf16x4*)(Y + base) = o;
}

// ---- combine: out[node][f] = act(h0*Y0 + h1*Y1 + h2*sum(P) + b[f]) ----
// P/Y0t/Y1t are t-layout [f][8192]; output is row-major [node][F].
template<int RELU, int F32OUT>
__global__ void combine_out(const float* __restrict__ P,
                            const __bf16* __restrict__ Y0t,
                            const __bf16* __restrict__ Y1t,
                            const float* __restrict__ h,
                            const float* __restrict__ bias,
                            void* __restrict__ outp,
                            int F, int SP) {
    const int i = blockIdx.x * blockDim.x + threadIdx.x;  // (f, node4)
    const int total = F * 2048;
    if (i >= total) return;
    const int f  = i >> 11;           // / 2048
    const int n4 = i & 2047;
    const size_t base = (size_t)f * 8192 + (size_t)n4 * 4;
    const int MN = F * 8192;

    float4 s = *(const float4*)(P + base);
    for (int sp = 1; sp < SP; sp++) {
        float4 v = *(const float4*)(P + (size_t)sp * MN + base);
        s.x += v.x; s.y += v.y; s.z += v.z; s.w += v.w;
    }
    bf16x4 y0 = *(const bf16x4*)(Y0t + base);
    bf16x4 y1 = *(const bf16x4*)(Y1t + base);
    const float h0 = h[0], h1 = h[1], h2 = h[2], bb = bias[f];

    float v[4] = {s.x, s.y, s.z, s.w};
    #pragma unroll
    for (int r = 0; r < 4; r++) {
        float x = h0 * (float)y0[r] + h1 * (float)y1[r] + h2 * v[r] + bb;
        if (RELU) x = fmaxf(x, 0.0f);
        v[r] = x;
    }
    const int node = n4 * 4;
    if (F32OUT) {
        float* O = (float*)outp;
        #pragma unroll
        for (int r = 0; r < 4; r++) O[(size_t)(node + r) * F + f] = v[r];
    } else {
        __bf16* O = (__bf16*)outp;
        #pragma unroll
        for (int r = 0; r < 4; r++) O[(size_t)(node + r) * F + f] = (__bf16)v[r];
    }
}

extern "C" void kernel_launch(void* const* d_in, const int* in_sizes, int n_in,
                              void* d_out, int out_size, void* d_ws, size_t ws_size,
                              hipStream_t stream) {
    const float* S  = (const float*)d_in[0];
    const float* X  = (const float*)d_in[1];
    const float* W1 = (const float*)d_in[2];
    const float* h1 = (const float*)d_in[3];
    const float* b1 = (const float*)d_in[4];
    const float* W2 = (const float*)d_in[5];
    const float* h2 = (const float*)d_in[6];
    const float* b2 = (const float*)d_in[7];
    const float* W3 = (const float*)d_in[8];
    const float* h3 = (const float*)d_in[9];
    const float* b3 = (const float*)d_in[10];
    float* out = (float*)d_out;

    const int Nn = 8192, IN = 512, HID = 128, OUT = 64;

    char* ws = (char*)d_ws;
    size_t off = 0;
    auto carve = [&](size_t bytes) -> void* {
        void* p = ws + off;
        off += (bytes + 255) & ~(size_t)255;
        return p;
    };
    __bf16* Sb  = (__bf16*)carve((size_t)Nn * Nn  * 2);   // 134.2 MB
    __bf16* Xb  = (__bf16*)carve((size_t)Nn * IN  * 2);   // 8.4 MB
    __bf16* W1t = (__bf16*)carve((size_t)IN  * HID * 2);
    __bf16* W2t = (__bf16*)carve((size_t)HID * HID * 2);
    __bf16* W3t = (__bf16*)carve((size_t)HID * OUT * 2);
    __bf16* Y0t = (__bf16*)carve((size_t)HID * Nn * 2);   // [F][8192]
    __bf16* Y1t = (__bf16*)carve((size_t)HID * Nn * 2);
    __bf16* Act = (__bf16*)carve((size_t)Nn * HID * 2);   // [node][F]
    size_t  base = off;

    // split-K factor adaptive to remaining workspace (4 MB per split @F=128)
    const size_t per_split = (size_t)HID * Nn * 4;
    int SP = 1;
    while (SP < 8 && base + (size_t)(SP * 2) * per_split <= ws_size) SP *= 2;
    float* P = (float*)carve((size_t)SP * per_split);
    const int KCH = Nn / SP;

    // ---- converts ----
    {
        int n4 = Nn * Nn / 4;
        cvt_f32_bf16<<<dim3((n4 + 255) / 256), dim3(256), 0, stream>>>(
            (const float4*)S, (bf16x4*)Sb, n4);
        n4 = Nn * IN / 4;
        cvt_f32_bf16<<<dim3((n4 + 255) / 256), dim3(256), 0, stream>>>(
            (const float4*)X, (bf16x4*)Xb, n4);
    }
    cvt_transpose<<<dim3((IN * HID + 255) / 256), dim3(256), 0, stream>>>(W1, W1t, IN, HID);
    cvt_transpose<<<dim3((HID * HID + 255) / 256), dim3(256), 0, stream>>>(W2, W2t, HID, HID);
    cvt_transpose<<<dim3((HID * OUT + 255) / 256), dim3(256), 0, stream>>>(W3, W3t, HID, OUT);

    // S-GEMM: partials P[s][f][node];  A=Sb ldA=8192, B=Yt ldB=8192
    auto sgemm = [&](const __bf16* Bt, int F) {
        if (F == 128)
            gemm_rd<2, 8, 0><<<dim3(Nn / 128, 1, SP), dim3(256), 0, stream>>>(
                Sb, Bt, P, Nn, KCH, Nn, F);
        else
            gemm_rd<2, 4, 0><<<dim3(Nn / 128, 1, SP), dim3(256), 0, stream>>>(
                Sb, Bt, P, Nn, KCH, Nn, F);
    };
    auto reduceY = [&](__bf16* Y, int F) {
        int t4 = F * 2048;
        reduce_partials<<<dim3((t4 + 255) / 256), dim3(256), 0, stream>>>(
            P, Y, t4, SP, F * Nn);
    };

    // ---- layer 1 ----
    // Y0t = W1t @ Xb   (M=128, N=8192, K=512)
    gemm_rd<2, 4, 1><<<dim3(1, Nn / 64, 1), dim3(256), 0, stream>>>(
        W1t, Xb, Y0t, IN, IN, HID, Nn);
    sgemm(Y0t, HID);                       // P = split-partials of S@Y0
    reduceY(Y1t, HID);                     // Y1t = S@Y0
    sgemm(Y1t, HID);                       // P = split-partials of S@Y1
    combine_out<1, 0><<<dim3(HID * 2048 / 256), dim3(256), 0, stream>>>(
        P, Y0t, Y1t, h1, b1, Act, HID, SP);

    // ---- layer 2 ----
    gemm_rd<2, 4, 1><<<dim3(1, Nn / 64, 1), dim3(256), 0, stream>>>(
        W2t, Act, Y0t, HID, HID, HID, Nn);
    sgemm(Y0t, HID);
    reduceY(Y1t, HID);
    sgemm(Y1t, HID);
    combine_out<1, 0><<<dim3(HID * 2048 / 256), dim3(256), 0, stream>>>(
        P, Y0t, Y1t, h2, b2, Act, HID, SP);

    // ---- layer 3 (F=64, fp32 out, no relu) ----
    gemm_rd<1, 4, 1><<<dim3(1, Nn / 64, 1), dim3(256), 0, stream>>>(
        W3t, Act, Y0t, HID, HID, OUT, Nn);
    sgemm(Y0t, OUT);
    reduceY(Y1t, OUT);
    sgemm(Y1t, OUT);
    combine_out<0, 1><<<dim3(OUT * 2048 / 256), dim3(256), 0, stream>>>(
        P, Y0t, Y1t, h3, b3, out, OUT, SP);

    (void)in_sizes; (void)n_in; (void)out_size;
}